// Round 3
// baseline (1195.380 us; speedup 1.0000x reference)
//
#include <hip/hip_runtime.h>
#include <hip/hip_bf16.h>

typedef __bf16 bf16;
typedef __bf16 bf16x4 __attribute__((ext_vector_type(4)));
typedef __bf16 bf16x8 __attribute__((ext_vector_type(8)));
typedef float f32x4 __attribute__((ext_vector_type(4)));

#define GLD16(gp, sp) __builtin_amdgcn_global_load_lds( \
    (const __attribute__((address_space(1))) void*)(gp), \
    (__attribute__((address_space(3))) void*)(sp), 16, 0, 0)

constexpr int UNITS = 8;
constexpr int BATCH = 65536;
constexpr int DIM   = 256;    // I == H == 256
constexpr int BM = 128;       // rows per block
constexpr int BN = 32;        // H-columns per block
constexpr int BK = 64;        // K-chunk
constexpr int NW = 4;         // waves per block

constexpr size_t XN = (size_t)BATCH * DIM;            // 16,777,216
constexpr size_t WN = (size_t)UNITS * 3 * DIM * DIM;  // 1,572,864 (per weight tensor)

__device__ __forceinline__ float sigmoidf_fast(float x) {
    return 1.0f / (1.0f + __expf(-x));
}
__device__ __forceinline__ float tanhf_fast(float x) {
    float y = fminf(fmaxf(x, -15.0f), 15.0f);   // clamp: avoid inf/inf NaN
    float e = __expf(-2.0f * y);
    return (1.0f - e) / (1.0f + e);
}

// f32 -> bf16 (RNE) bulk convert of x, W_ih, W_hh, h0 into workspace.
// Inputs are float32 per the reference; bf16 is only our internal MFMA format.
__global__ void convert_kernel(const float* __restrict__ x,
                               const float* __restrict__ Wih,
                               const float* __restrict__ Whh,
                               const float* __restrict__ h0,
                               bf16* __restrict__ xbf,
                               bf16* __restrict__ Wihbf,
                               bf16* __restrict__ Whhbf,
                               bf16* __restrict__ h0bf)
{
    const size_t total4 = (XN + 2 * WN + DIM) / 4;
    size_t i4 = (size_t)blockIdx.x * blockDim.x + threadIdx.x;
    if (i4 >= total4) return;
    size_t e = i4 * 4;
    const float* src; bf16* dst; size_t off;
    if (e < XN)               { src = x;   dst = xbf;   off = e; }
    else if (e < XN + WN)     { src = Wih; dst = Wihbf; off = e - XN; }
    else if (e < XN + 2 * WN) { src = Whh; dst = Whhbf; off = e - XN - WN; }
    else                      { src = h0;  dst = h0bf;  off = e - XN - 2 * WN; }
    const float4 v = *(const float4*)(src + off);
    bf16x4 o;
    o[0] = (bf16)v.x; o[1] = (bf16)v.y; o[2] = (bf16)v.z; o[3] = (bf16)v.w;
    *(bf16x4*)(dst + off) = o;
}

// One GRU cell: out = GRU(x, h_prev) for one unit's weights.
// 6 fused GEMM accumulations [BM x BN, K=256] + gate epilogue.
__global__ __launch_bounds__(256, 2)
void gru_unit_kernel(const bf16* __restrict__ x,       // [B,256] bf16
                     const bf16* __restrict__ h_prev,  // [B,256] bf16 (or h0[256] w/ stride 0)
                     long h_row_stride,
                     const bf16* __restrict__ Wih,     // [768,256] bf16 unit slice
                     const bf16* __restrict__ Whh,     // [768,256] bf16
                     const float* __restrict__ bih,    // [768] f32
                     const float* __restrict__ bhh,    // [768] f32
                     bf16* __restrict__ out_bf,        // [B,256] bf16 (intermediate) or null
                     float* __restrict__ out_f32)      // [B,256] f32 (final) or null
{
    __shared__ __align__(16) bf16 xs[BM * BK];      // 16 KB
    __shared__ __align__(16) bf16 hs[BM * BK];      // 16 KB
    __shared__ __align__(16) bf16 wi[3 * BN * BK];  // 12 KB (r,z,n row groups)
    __shared__ __align__(16) bf16 wh[3 * BN * BK];  // 12 KB

    const int tid  = threadIdx.x;
    const int wave = tid >> 6;
    const int lane = tid & 63;
    const int quad = lane >> 4;
    const int l15  = lane & 15;

    const int m0 = blockIdx.x * BM;
    const int j0 = blockIdx.y * BN;

    // staging: each global_load_lds call moves 1 KB = 8 rows x 64 bf16.
    // lane l writes LDS slot l (16B); slot-in-row = l&7, row-in-chunk = l>>3.
    // XOR swizzle: LDS slot s of row r holds global k-slot (s ^ (r&7)),
    // so the lane FETCHES global slot (l&7)^(lrow&7). Breaks the 16-way
    // bank conflict on fragment ds_read_b128 down to 2-way (free, m136).
    const int lrow  = lane >> 3;
    const int gslot = (lane & 7) ^ (lrow & 7);
    const int gcol  = gslot * 8;   // element offset within BK

    f32x4 accx[3][2][2];   // gates r,z,n from x @ Wih^T : [g][mt][tn]
    f32x4 acch[3][2][2];   // gates r,z,n from h @ Whh^T
#pragma unroll
    for (int g = 0; g < 3; ++g)
#pragma unroll
        for (int mt = 0; mt < 2; ++mt)
#pragma unroll
            for (int tn = 0; tn < 2; ++tn) {
                accx[g][mt][tn] = (f32x4){0.f, 0.f, 0.f, 0.f};
                acch[g][mt][tn] = (f32x4){0.f, 0.f, 0.f, 0.f};
            }

    for (int kc = 0; kc < DIM / BK; ++kc) {
        const int k0 = kc * BK;
        __syncthreads();   // LDS free to overwrite

        // 56 x 1KB chunks: x 16, h 16, wi 12, wh 12 — round-robin by wave
        for (int c = wave; c < 56; c += NW) {
            if (c < 16) {
                const int row = c * 8 + lrow;
                GLD16(x + (size_t)(m0 + row) * DIM + k0 + gcol, xs + c * 512);
            } else if (c < 32) {
                const int row = (c - 16) * 8 + lrow;
                GLD16(h_prev + (size_t)(m0 + row) * h_row_stride + k0 + gcol,
                      hs + (c - 16) * 512);
            } else if (c < 44) {
                const int lr = (c - 32) * 8 + lrow;        // 0..95
                const int grow = (lr >> 5) * DIM + j0 + (lr & 31);
                GLD16(Wih + (size_t)grow * DIM + k0 + gcol, wi + (c - 32) * 512);
            } else {
                const int lr = (c - 44) * 8 + lrow;
                const int grow = (lr >> 5) * DIM + j0 + (lr & 31);
                GLD16(Whh + (size_t)grow * DIM + k0 + gcol, wh + (c - 44) * 512);
            }
        }
        __syncthreads();   // staging visible (compiler drains vmcnt at barrier)

#pragma unroll
        for (int ks = 0; ks < 2; ++ks) {
            const int kb = ks * 4 + quad;   // 16B k-slot index 0..7
            bf16x8 ax[2], ah[2];
#pragma unroll
            for (int mt = 0; mt < 2; ++mt) {
                const int r = wave * 32 + mt * 16 + l15;
                const int off = r * BK + ((kb ^ (r & 7)) * 8);
                ax[mt] = *(const bf16x8*)(xs + off);
                ah[mt] = *(const bf16x8*)(hs + off);
            }
#pragma unroll
            for (int g = 0; g < 3; ++g) {
                const int r0 = g * BN + l15;
                const int r1 = g * BN + 16 + l15;
                const int o0 = r0 * BK + ((kb ^ (r0 & 7)) * 8);
                const int o1 = r1 * BK + ((kb ^ (r1 & 7)) * 8);
                const bf16x8 bi0 = *(const bf16x8*)(wi + o0);
                const bf16x8 bi1 = *(const bf16x8*)(wi + o1);
                const bf16x8 bh0 = *(const bf16x8*)(wh + o0);
                const bf16x8 bh1 = *(const bf16x8*)(wh + o1);
#pragma unroll
                for (int mt = 0; mt < 2; ++mt) {
                    accx[g][mt][0] = __builtin_amdgcn_mfma_f32_16x16x32_bf16(ax[mt], bi0, accx[g][mt][0], 0, 0, 0);
                    accx[g][mt][1] = __builtin_amdgcn_mfma_f32_16x16x32_bf16(ax[mt], bi1, accx[g][mt][1], 0, 0, 0);
                    acch[g][mt][0] = __builtin_amdgcn_mfma_f32_16x16x32_bf16(ah[mt], bh0, acch[g][mt][0], 0, 0, 0);
                    acch[g][mt][1] = __builtin_amdgcn_mfma_f32_16x16x32_bf16(ah[mt], bh1, acch[g][mt][1], 0, 0, 0);
                }
            }
        }
    }

    // Epilogue: C/D layout col = lane&15, row = quad*4 + reg (m89-verified).
#pragma unroll
    for (int tn = 0; tn < 2; ++tn) {
        const int jc = j0 + tn * 16 + l15;
        const float br  = bih[jc]           + bhh[jc];
        const float bz  = bih[DIM + jc]     + bhh[DIM + jc];
        const float bni = bih[2 * DIM + jc];
        const float bnh = bhh[2 * DIM + jc];
#pragma unroll
        for (int mt = 0; mt < 2; ++mt) {
            const int row0 = m0 + wave * 32 + mt * 16 + quad * 4;
#pragma unroll
            for (int i = 0; i < 4; ++i) {
                const size_t idx = (size_t)(row0 + i) * DIM + jc;
                const float sr = accx[0][mt][tn][i] + acch[0][mt][tn][i] + br;
                const float sz = accx[1][mt][tn][i] + acch[1][mt][tn][i] + bz;
                const float pi = accx[2][mt][tn][i] + bni;
                const float ph = acch[2][mt][tn][i] + bnh;
                const float r = sigmoidf_fast(sr);
                const float z = sigmoidf_fast(sz);
                const float n = tanhf_fast(pi + r * ph);
                const float hp = (float)h_prev[(size_t)(row0 + i) * h_row_stride + jc];
                const float hv = (1.0f - z) * n + z * hp;
                if (out_f32) out_f32[idx] = hv;
                else         out_bf[idx] = (bf16)hv;
            }
        }
    }
}

extern "C" void kernel_launch(void* const* d_in, const int* in_sizes, int n_in,
                              void* d_out, int out_size, void* d_ws, size_t ws_size,
                              hipStream_t stream) {
    const float* x   = (const float*)d_in[0];
    const float* Wih = (const float*)d_in[1];   // [8,768,256] f32
    const float* Whh = (const float*)d_in[2];   // [8,768,256] f32
    const float* bih = (const float*)d_in[3];   // [8,768] f32
    const float* bhh = (const float*)d_in[4];   // [8,768] f32
    const float* h0  = (const float*)d_in[5];   // [256] f32
    float* out = (float*)d_out;                 // [B,256] f32

    // ws layout (bf16 elements): xbf[XN] | Wihbf[WN] | Whhbf[WN] | h0bf[256] | hA[XN]
    bf16* xbf   = (bf16*)d_ws;
    bf16* Wihbf = xbf + XN;
    bf16* Whhbf = Wihbf + WN;
    bf16* h0bf  = Whhbf + WN;
    bf16* hA    = h0bf + 256;              // ws total ~74 MB
    // hB: reuse d_out storage (first 33.5 MB of the 67 MB f32 out buffer).
    // Safe: unit 7 reads hA and overwrites all of d_out with f32.
    bf16* hB    = (bf16*)d_out;

    {   // f32 -> bf16 conversions (runs every call; ws is re-poisoned each launch)
        const size_t total4 = (XN + 2 * WN + DIM) / 4;
        const int cblocks = (int)((total4 + 255) / 256);
        hipLaunchKernelGGL(convert_kernel, dim3(cblocks), dim3(256), 0, stream,
                           x, Wih, Whh, h0, xbf, Wihbf, Whhbf, h0bf);
    }

    dim3 grid(BATCH / BM, DIM / BN);
    dim3 block(256);

    // ping-pong: u0 h0->hA, u1 hA->hB, u2 hB->hA, ... u7 hA->out(f32)
    for (int u = 0; u < UNITS; ++u) {
        const bf16* hp; long hstride;
        if (u == 0)      { hp = h0bf; hstride = 0; }   // h0 broadcast (row-stride 0)
        else if (u & 1)  { hp = hA;   hstride = DIM; } // odd units read A
        else             { hp = hB;   hstride = DIM; } // even units read B
        bf16* ob = nullptr; float* of = nullptr;
        if (u == UNITS - 1) of = out;
        else ob = (u & 1) ? hB : hA;
        hipLaunchKernelGGL(gru_unit_kernel, grid, block, 0, stream,
                           xbf, hp, hstride,
                           Wihbf + (size_t)u * 3 * DIM * DIM,
                           Whhbf + (size_t)u * 3 * DIM * DIM,
                           bih + (size_t)u * 3 * DIM,
                           bhh + (size_t)u * 3 * DIM,
                           ob, of);
    }
}

// Round 4
// 1067.743 us; speedup vs baseline: 1.1195x; 1.1195x over previous
//
#include <hip/hip_runtime.h>
#include <hip/hip_bf16.h>

typedef __bf16 bf16;
typedef __bf16 bf16x4 __attribute__((ext_vector_type(4)));
typedef __bf16 bf16x8 __attribute__((ext_vector_type(8)));
typedef float f32x4 __attribute__((ext_vector_type(4)));

#define GLD16(gp, sp) __builtin_amdgcn_global_load_lds( \
    (const __attribute__((address_space(1))) void*)(gp), \
    (__attribute__((address_space(3))) void*)(sp), 16, 0, 0)

constexpr int UNITS = 8;
constexpr int BATCH = 65536;
constexpr int DIM   = 256;    // I == H == 256
constexpr int BM = 128;       // rows per block
constexpr int BN = 32;        // H-columns per block
constexpr int BK = 32;        // K-chunk (32 => 28KB LDS => 4 blocks/CU, and
                              // bank-even b128 reads with NO swizzle)
constexpr int NW = 4;         // waves per block

constexpr size_t XN = (size_t)BATCH * DIM;            // 16,777,216
constexpr size_t WN = (size_t)UNITS * 3 * DIM * DIM;  // 1,572,864 (per weight tensor)

__device__ __forceinline__ float sigmoidf_fast(float x) {
    return 1.0f / (1.0f + __expf(-x));
}
__device__ __forceinline__ float tanhf_fast(float x) {
    float y = fminf(fmaxf(x, -15.0f), 15.0f);   // clamp: avoid inf/inf NaN
    float e = __expf(-2.0f * y);
    return (1.0f - e) / (1.0f + e);
}

// f32 -> bf16 (RNE) bulk convert of x, W_ih, W_hh, h0 into workspace.
__global__ void convert_kernel(const float* __restrict__ x,
                               const float* __restrict__ Wih,
                               const float* __restrict__ Whh,
                               const float* __restrict__ h0,
                               bf16* __restrict__ xbf,
                               bf16* __restrict__ Wihbf,
                               bf16* __restrict__ Whhbf,
                               bf16* __restrict__ h0bf)
{
    const size_t total4 = (XN + 2 * WN + DIM) / 4;
    size_t i4 = (size_t)blockIdx.x * blockDim.x + threadIdx.x;
    if (i4 >= total4) return;
    size_t e = i4 * 4;
    const float* src; bf16* dst; size_t off;
    if (e < XN)               { src = x;   dst = xbf;   off = e; }
    else if (e < XN + WN)     { src = Wih; dst = Wihbf; off = e - XN; }
    else if (e < XN + 2 * WN) { src = Whh; dst = Whhbf; off = e - XN - WN; }
    else                      { src = h0;  dst = h0bf;  off = e - XN - 2 * WN; }
    const float4 v = *(const float4*)(src + off);
    bf16x4 o;
    o[0] = (bf16)v.x; o[1] = (bf16)v.y; o[2] = (bf16)v.z; o[3] = (bf16)v.w;
    *(bf16x4*)(dst + off) = o;
}

// One GRU cell. Gates r,z use MERGED accumulators (x@Wih_g and h@Whh_g chain
// into the same acc — only gate n needs i_n and h_n separate for r*h_n).
// acc groups: 0=r, 1=z, 2=n_i, 3=n_h  -> 16 f32x4 = 64 acc VGPRs.
__global__ __launch_bounds__(256, 4)
void gru_unit_kernel(const bf16* __restrict__ x,       // [B,256] bf16
                     const bf16* __restrict__ h_prev,  // [B,256] bf16 (or h0[256] w/ stride 0)
                     long h_row_stride,
                     const bf16* __restrict__ Wih,     // [768,256] bf16 unit slice
                     const bf16* __restrict__ Whh,     // [768,256] bf16
                     const float* __restrict__ bih,    // [768] f32
                     const float* __restrict__ bhh,    // [768] f32
                     bf16* __restrict__ out_bf,        // [B,256] bf16 (intermediate) or null
                     float* __restrict__ out_f32)      // [B,256] f32 (final) or null
{
    __shared__ __align__(16) bf16 xs[BM * BK];      // 8 KB
    __shared__ __align__(16) bf16 hs[BM * BK];      // 8 KB
    __shared__ __align__(16) bf16 wi[3 * BN * BK];  // 6 KB (r,z,n row groups)
    __shared__ __align__(16) bf16 wh[3 * BN * BK];  // 6 KB   => 28 KB total

    const int tid  = threadIdx.x;
    const int wave = tid >> 6;
    const int lane = tid & 63;
    const int quad = lane >> 4;
    const int l15  = lane & 15;

    // grid: blockIdx.x = j-tile (FAST: pins each j-tile to one XCD -> weight
    // slice stays L2-resident; x/h m-tiles broadcast via L3), blockIdx.y = m.
    const int j0 = blockIdx.x * BN;
    const int m0 = blockIdx.y * BM;

    // staging: one GLD16 chunk = 1 KB = 16 rows x 32 bf16 (lane l -> row l>>2,
    // col (l&3)*8; LDS dst = base + l*16B, contiguous in lane order).
    const int srow = lane >> 2;
    const int scol = (lane & 3) * 8;

    f32x4 acc[4][2][2];   // [r,z,ni,nh][mt][tn]
#pragma unroll
    for (int g = 0; g < 4; ++g)
#pragma unroll
        for (int mt = 0; mt < 2; ++mt)
#pragma unroll
            for (int tn = 0; tn < 2; ++tn)
                acc[g][mt][tn] = (f32x4){0.f, 0.f, 0.f, 0.f};

    for (int kc = 0; kc < DIM / BK; ++kc) {
        const int k0 = kc * BK;
        __syncthreads();   // LDS free to overwrite

        // 28 x 1KB chunks: x 8, h 8, wi 6, wh 6 — round-robin by wave
        for (int c = wave; c < 28; c += NW) {
            if (c < 8) {
                const int row = c * 16 + srow;
                GLD16(x + (size_t)(m0 + row) * DIM + k0 + scol, xs + c * 512);
            } else if (c < 16) {
                const int row = (c - 8) * 16 + srow;
                GLD16(h_prev + (size_t)(m0 + row) * h_row_stride + k0 + scol,
                      hs + (c - 8) * 512);
            } else if (c < 22) {
                const int lr = (c - 16) * 16 + srow;        // 0..95
                const int grow = (lr >> 5) * DIM + j0 + (lr & 31);
                GLD16(Wih + (size_t)grow * DIM + k0 + scol, wi + (c - 16) * 512);
            } else {
                const int lr = (c - 22) * 16 + srow;
                const int grow = (lr >> 5) * DIM + j0 + (lr & 31);
                GLD16(Whh + (size_t)grow * DIM + k0 + scol, wh + (c - 22) * 512);
            }
        }
        __syncthreads();   // staging visible

        // one MFMA K-step per kc: A-frag k = quad*8..+8 (BK=32 exactly)
        const int koff = quad * 8;
        bf16x8 ax[2], ah[2];
#pragma unroll
        for (int mt = 0; mt < 2; ++mt) {
            const int r = wave * 32 + mt * 16 + l15;
            ax[mt] = *(const bf16x8*)(xs + r * BK + koff);
            ah[mt] = *(const bf16x8*)(hs + r * BK + koff);
        }
#pragma unroll
        for (int g = 0; g < 3; ++g) {
            const int r0 = g * BN + l15;
            const int r1 = g * BN + 16 + l15;
            const bf16x8 bi0 = *(const bf16x8*)(wi + r0 * BK + koff);
            const bf16x8 bi1 = *(const bf16x8*)(wi + r1 * BK + koff);
            const bf16x8 bh0 = *(const bf16x8*)(wh + r0 * BK + koff);
            const bf16x8 bh1 = *(const bf16x8*)(wh + r1 * BK + koff);
            if (g < 2) {   // r, z: merged accumulation
#pragma unroll
                for (int mt = 0; mt < 2; ++mt) {
                    acc[g][mt][0] = __builtin_amdgcn_mfma_f32_16x16x32_bf16(ax[mt], bi0, acc[g][mt][0], 0, 0, 0);
                    acc[g][mt][1] = __builtin_amdgcn_mfma_f32_16x16x32_bf16(ax[mt], bi1, acc[g][mt][1], 0, 0, 0);
                    acc[g][mt][0] = __builtin_amdgcn_mfma_f32_16x16x32_bf16(ah[mt], bh0, acc[g][mt][0], 0, 0, 0);
                    acc[g][mt][1] = __builtin_amdgcn_mfma_f32_16x16x32_bf16(ah[mt], bh1, acc[g][mt][1], 0, 0, 0);
                }
            } else {       // n: split accumulators
#pragma unroll
                for (int mt = 0; mt < 2; ++mt) {
                    acc[2][mt][0] = __builtin_amdgcn_mfma_f32_16x16x32_bf16(ax[mt], bi0, acc[2][mt][0], 0, 0, 0);
                    acc[2][mt][1] = __builtin_amdgcn_mfma_f32_16x16x32_bf16(ax[mt], bi1, acc[2][mt][1], 0, 0, 0);
                    acc[3][mt][0] = __builtin_amdgcn_mfma_f32_16x16x32_bf16(ah[mt], bh0, acc[3][mt][0], 0, 0, 0);
                    acc[3][mt][1] = __builtin_amdgcn_mfma_f32_16x16x32_bf16(ah[mt], bh1, acc[3][mt][1], 0, 0, 0);
                }
            }
        }
    }

    // Epilogue: C/D layout col = lane&15, row = quad*4 + reg (m89-verified).
#pragma unroll
    for (int tn = 0; tn < 2; ++tn) {
        const int jc = j0 + tn * 16 + l15;
        const float br  = bih[jc]           + bhh[jc];
        const float bz  = bih[DIM + jc]     + bhh[DIM + jc];
        const float bni = bih[2 * DIM + jc];
        const float bnh = bhh[2 * DIM + jc];
#pragma unroll
        for (int mt = 0; mt < 2; ++mt) {
            const int row0 = m0 + wave * 32 + mt * 16 + quad * 4;
#pragma unroll
            for (int i = 0; i < 4; ++i) {
                const size_t idx = (size_t)(row0 + i) * DIM + jc;
                const float r = sigmoidf_fast(acc[0][mt][tn][i] + br);
                const float z = sigmoidf_fast(acc[1][mt][tn][i] + bz);
                const float n = tanhf_fast(acc[2][mt][tn][i] + bni
                                           + r * (acc[3][mt][tn][i] + bnh));
                const float hp = (float)h_prev[(size_t)(row0 + i) * h_row_stride + jc];
                const float hv = (1.0f - z) * n + z * hp;
                if (out_f32) out_f32[idx] = hv;
                else         out_bf[idx] = (bf16)hv;
            }
        }
    }
}

extern "C" void kernel_launch(void* const* d_in, const int* in_sizes, int n_in,
                              void* d_out, int out_size, void* d_ws, size_t ws_size,
                              hipStream_t stream) {
    const float* x   = (const float*)d_in[0];
    const float* Wih = (const float*)d_in[1];   // [8,768,256] f32
    const float* Whh = (const float*)d_in[2];   // [8,768,256] f32
    const float* bih = (const float*)d_in[3];   // [8,768] f32
    const float* bhh = (const float*)d_in[4];   // [8,768] f32
    const float* h0  = (const float*)d_in[5];   // [256] f32
    float* out = (float*)d_out;                 // [B,256] f32

    // ws layout (bf16 elements): xbf[XN] | Wihbf[WN] | Whhbf[WN] | h0bf[256] | hA[XN]
    bf16* xbf   = (bf16*)d_ws;
    bf16* Wihbf = xbf + XN;
    bf16* Whhbf = Wihbf + WN;
    bf16* h0bf  = Whhbf + WN;
    bf16* hA    = h0bf + 256;              // ws total ~74 MB
    // hB: reuse d_out storage (unit 7 reads hA and overwrites d_out with f32).
    bf16* hB    = (bf16*)d_out;

    {   // f32 -> bf16 conversions
        const size_t total4 = (XN + 2 * WN + DIM) / 4;
        const int cblocks = (int)((total4 + 255) / 256);
        hipLaunchKernelGGL(convert_kernel, dim3(cblocks), dim3(256), 0, stream,
                           x, Wih, Whh, h0, xbf, Wihbf, Whhbf, h0bf);
    }

    dim3 grid(DIM / BN, BATCH / BM);   // (8 j-tiles FAST, 512 m-tiles)
    dim3 block(256);

    // ping-pong: u0 h0->hA, u1 hA->hB, u2 hB->hA, ... u7 hA->out(f32)
    for (int u = 0; u < UNITS; ++u) {
        const bf16* hp; long hstride;
        if (u == 0)      { hp = h0bf; hstride = 0; }   // h0 broadcast (row-stride 0)
        else if (u & 1)  { hp = hA;   hstride = DIM; } // odd units read A
        else             { hp = hB;   hstride = DIM; } // even units read B
        bf16* ob = nullptr; float* of = nullptr;
        if (u == UNITS - 1) of = out;
        else ob = (u & 1) ? hB : hA;
        hipLaunchKernelGGL(gru_unit_kernel, grid, block, 0, stream,
                           xbf, hp, hstride,
                           Wihbf + (size_t)u * 3 * DIM * DIM,
                           Whhbf + (size_t)u * 3 * DIM * DIM,
                           bih + (size_t)u * 3 * DIM,
                           bhh + (size_t)u * 3 * DIM,
                           ob, of);
    }
}